// Round 6
// baseline (156.428 us; speedup 1.0000x reference)
//
#include <hip/hip_runtime.h>

#define STEPS   2000
#define DT_F    0.001f
#define EPS_F   1e-6f
#define MAXT_F  2.0f
#define CHUNK   8
#define NCHUNK  (STEPS / CHUNK)   // 250
// R6 change vs R5: 2 trials per thread, float2 (8 B/lane) noise loads ->
// half the VMEM instruction count for the same bytes. Pipeline structure
// (8 rotating buffers, depth-7 prefetch = 56 outstanding <= vmcnt cap,
// nontemporal) identical to the verified R5.

typedef float v2f __attribute__((ext_vector_type(2)));

#define LOADC(BUF, c_) do {                                                   \
    const int cc = ((c_) < NCHUNK) ? (c_) : (NCHUNK - 1);                     \
    const v2f* bp = p + (size_t)(cc * CHUNK) * stride2;                       \
    _Pragma("unroll")                                                         \
    for (int k = 0; k < CHUNK; ++k)                                           \
        BUF[k] = __builtin_nontemporal_load(bp + (size_t)k * stride2);        \
} while (0)

// Exact reference rounding per trial: dv = ((dv + drift*DT) + nscale*nz),
// separate mul/add, no FMA. Branchless hit latch: single abs-compare
// (fl(EPS-a) == -fl(a-EPS) under RN symmetry -> identical to the two-sided
// test) + cndmask latches; rt/choice math deferred to the epilogue.
#define STEPC(BUF, cbase) do {                                                \
    _Pragma("unroll")                                                         \
    for (int k = 0; k < CHUNK; ++k) {                                         \
        dv0 = __fadd_rn(__fadd_rn(dv0, ddt0), __fmul_rn(nscale, BUF[k].x));   \
        dv1 = __fadd_rn(__fadd_rn(dv1, ddt1), __fmul_rn(nscale, BUF[k].y));   \
        const bool h0 = act0 && (__builtin_fabsf(dv0) >= a_hi);               \
        const bool h1 = act1 && (__builtin_fabsf(dv1) >= a_hi);               \
        t_hit0  = h0 ? ((cbase) * CHUNK + k) : t_hit0;                        \
        t_hit1  = h1 ? ((cbase) * CHUNK + k) : t_hit1;                        \
        dv_hit0 = h0 ? dv0 : dv_hit0;                                         \
        dv_hit1 = h1 ? dv1 : dv_hit1;                                         \
        act0    = act0 && !h0;                                                \
        act1    = act1 && !h1;                                                \
    }                                                                         \
} while (0)

__global__ __launch_bounds__(256, 1) void ddm_sim_kernel(
    const float* __restrict__ x,
    const float* __restrict__ noise,
    const float* __restrict__ p_a,
    const float* __restrict__ p_z,
    const float* __restrict__ p_ndt,
    const float* __restrict__ p_dg,
    float* __restrict__ out,   // [0,n) = pred_rt, [n,2n) = pred_choice
    int n)
{
    const int j = blockIdx.x * blockDim.x + threadIdx.x;  // pair index
    const int i0 = 2 * j;
    if (i0 >= n) return;

    const float a   = *p_a;
    const float z   = *p_z;
    const float ndt = *p_ndt;
    const float dg  = *p_dg;

    const float ddt0   = __fmul_rn(__fmul_rn(dg, x[i0]),     DT_F);
    const float ddt1   = __fmul_rn(__fmul_rn(dg, x[i0 + 1]), DT_F);
    const float nscale = __fsqrt_rn(DT_F);     // SIGMA(=1) * sqrt(DT)
    const float a_hi   = __fsub_rn(a, EPS_F);  // a - EPS

    float dv0 = __fmul_rn(z, a), dv1 = dv0;
    float dv_hit0 = 0.0f, dv_hit1 = 0.0f;
    int   t_hit0 = 0, t_hit1 = 0;
    bool  act0 = true, act1 = true;

    const v2f*   p       = (const v2f*)noise + j;
    const size_t stride2 = (size_t)(n >> 1);   // row stride in float2

    v2f B0[CHUNK], B1[CHUNK], B2[CHUNK], B3[CHUNK],
        B4[CHUNK], B5[CHUNK], B6[CHUNK], B7[CHUNK];

    // prologue: fill pipeline 7 deep (56 float2 loads in flight)
    LOADC(B0, 0);
    LOADC(B1, 1);
    LOADC(B2, 2);
    LOADC(B3, 3);
    LOADC(B4, 4);
    LOADC(B5, 5);
    LOADC(B6, 6);

    int c = 0;
    while (true) {
        LOADC(B7, c + 7); STEPC(B0, c); ++c; if (c >= NCHUNK || !__any(act0 || act1)) break;
        LOADC(B0, c + 7); STEPC(B1, c); ++c; if (c >= NCHUNK || !__any(act0 || act1)) break;
        LOADC(B1, c + 7); STEPC(B2, c); ++c; if (c >= NCHUNK || !__any(act0 || act1)) break;
        LOADC(B2, c + 7); STEPC(B3, c); ++c; if (c >= NCHUNK || !__any(act0 || act1)) break;
        LOADC(B3, c + 7); STEPC(B4, c); ++c; if (c >= NCHUNK || !__any(act0 || act1)) break;
        LOADC(B4, c + 7); STEPC(B5, c); ++c; if (c >= NCHUNK || !__any(act0 || act1)) break;
        LOADC(B5, c + 7); STEPC(B6, c); ++c; if (c >= NCHUNK || !__any(act0 || act1)) break;
        LOADC(B6, c + 7); STEPC(B7, c); ++c; if (c >= NCHUNK || !__any(act0 || act1)) break;
    }

    // epilogue: same pinned op sequence as the reference for rt/choice
    v2f rt, choice;
    rt.x     = act0 ? __fadd_rn(MAXT_F, ndt)
                    : __fadd_rn(__fmul_rn((float)t_hit0, DT_F), ndt);
    rt.y     = act1 ? __fadd_rn(MAXT_F, ndt)
                    : __fadd_rn(__fmul_rn((float)t_hit1, DT_F), ndt);
    choice.x = act0 ? 0.5f : ((dv_hit0 > 0.0f) ? 1.0f : 0.0f);
    choice.y = act1 ? 0.5f : ((dv_hit1 > 0.0f) ? 1.0f : 0.0f);

    __builtin_nontemporal_store(rt,     (v2f*)(out + i0));
    __builtin_nontemporal_store(choice, (v2f*)(out + n + i0));
}

extern "C" void kernel_launch(void* const* d_in, const int* in_sizes, int n_in,
                              void* d_out, int out_size, void* d_ws, size_t ws_size,
                              hipStream_t stream) {
    const float* x     = (const float*)d_in[0];
    const float* noise = (const float*)d_in[1];
    const float* a     = (const float*)d_in[2];
    const float* z     = (const float*)d_in[3];
    const float* ndt   = (const float*)d_in[4];
    const float* dg    = (const float*)d_in[5];
    float* out = (float*)d_out;

    const int n = in_sizes[0];              // 65536 trials (even)
    const int pairs = n >> 1;               // 32768 threads
    const int block = 256;
    const int grid  = (pairs + block - 1) / block;
    ddm_sim_kernel<<<grid, block, 0, stream>>>(x, noise, a, z, ndt, dg, out, n);
}

// Round 7
// 123.637 us; speedup vs baseline: 1.2652x; 1.2652x over previous
//
#include <hip/hip_runtime.h>

#define STEPS   2000
#define DT_F    0.001f
#define EPS_F   1e-6f
#define MAXT_F  2.0f
#define CHUNK   8
#define NCHUNK  (STEPS / CHUNK)   // 250
// R7 = R6 kernel with corrected launch geometry: block=128 -> grid=256 blocks
// -> ALL 256 CUs covered (R6's block=256 left half the CUs idle; per-CU BW
// ~26 GB/s capped the whole run at ~3.3 TB/s = the measured 156 us).
// 2 trials/thread, float2 (8 B/lane) nt loads; 8 rotating buffers, depth-7
// prefetch (56 outstanding <= vmcnt cap).

typedef float v2f __attribute__((ext_vector_type(2)));

#define LOADC(BUF, c_) do {                                                   \
    const int cc = ((c_) < NCHUNK) ? (c_) : (NCHUNK - 1);                     \
    const v2f* bp = p + (size_t)(cc * CHUNK) * stride2;                       \
    _Pragma("unroll")                                                         \
    for (int k = 0; k < CHUNK; ++k)                                           \
        BUF[k] = __builtin_nontemporal_load(bp + (size_t)k * stride2);        \
} while (0)

// Exact reference rounding per trial: dv = ((dv + drift*DT) + nscale*nz),
// separate mul/add, no FMA. Branchless hit latch: single abs-compare
// (fl(EPS-a) == -fl(a-EPS) under RN symmetry -> identical to the two-sided
// test) + cndmask latches; rt/choice math deferred to the epilogue.
#define STEPC(BUF, cbase) do {                                                \
    _Pragma("unroll")                                                         \
    for (int k = 0; k < CHUNK; ++k) {                                         \
        dv0 = __fadd_rn(__fadd_rn(dv0, ddt0), __fmul_rn(nscale, BUF[k].x));   \
        dv1 = __fadd_rn(__fadd_rn(dv1, ddt1), __fmul_rn(nscale, BUF[k].y));   \
        const bool h0 = act0 && (__builtin_fabsf(dv0) >= a_hi);               \
        const bool h1 = act1 && (__builtin_fabsf(dv1) >= a_hi);               \
        t_hit0  = h0 ? ((cbase) * CHUNK + k) : t_hit0;                        \
        t_hit1  = h1 ? ((cbase) * CHUNK + k) : t_hit1;                        \
        dv_hit0 = h0 ? dv0 : dv_hit0;                                         \
        dv_hit1 = h1 ? dv1 : dv_hit1;                                         \
        act0    = act0 && !h0;                                                \
        act1    = act1 && !h1;                                                \
    }                                                                         \
} while (0)

__global__ __launch_bounds__(128, 1) void ddm_sim_kernel(
    const float* __restrict__ x,
    const float* __restrict__ noise,
    const float* __restrict__ p_a,
    const float* __restrict__ p_z,
    const float* __restrict__ p_ndt,
    const float* __restrict__ p_dg,
    float* __restrict__ out,   // [0,n) = pred_rt, [n,2n) = pred_choice
    int n)
{
    const int j = blockIdx.x * blockDim.x + threadIdx.x;  // pair index
    const int i0 = 2 * j;
    if (i0 >= n) return;

    const float a   = *p_a;
    const float z   = *p_z;
    const float ndt = *p_ndt;
    const float dg  = *p_dg;

    const v2f   x2   = *(const v2f*)(x + i0);
    const float ddt0 = __fmul_rn(__fmul_rn(dg, x2.x), DT_F);
    const float ddt1 = __fmul_rn(__fmul_rn(dg, x2.y), DT_F);
    const float nscale = __fsqrt_rn(DT_F);     // SIGMA(=1) * sqrt(DT)
    const float a_hi   = __fsub_rn(a, EPS_F);  // a - EPS

    float dv0 = __fmul_rn(z, a), dv1 = dv0;
    float dv_hit0 = 0.0f, dv_hit1 = 0.0f;
    int   t_hit0 = 0, t_hit1 = 0;
    bool  act0 = true, act1 = true;

    const v2f*   p       = (const v2f*)noise + j;
    const size_t stride2 = (size_t)(n >> 1);   // row stride in float2

    v2f B0[CHUNK], B1[CHUNK], B2[CHUNK], B3[CHUNK],
        B4[CHUNK], B5[CHUNK], B6[CHUNK], B7[CHUNK];

    // prologue: fill pipeline 7 deep (56 float2 loads in flight)
    LOADC(B0, 0);
    LOADC(B1, 1);
    LOADC(B2, 2);
    LOADC(B3, 3);
    LOADC(B4, 4);
    LOADC(B5, 5);
    LOADC(B6, 6);

    int c = 0;
    while (true) {
        LOADC(B7, c + 7); STEPC(B0, c); ++c; if (c >= NCHUNK || !__any(act0 || act1)) break;
        LOADC(B0, c + 7); STEPC(B1, c); ++c; if (c >= NCHUNK || !__any(act0 || act1)) break;
        LOADC(B1, c + 7); STEPC(B2, c); ++c; if (c >= NCHUNK || !__any(act0 || act1)) break;
        LOADC(B2, c + 7); STEPC(B3, c); ++c; if (c >= NCHUNK || !__any(act0 || act1)) break;
        LOADC(B3, c + 7); STEPC(B4, c); ++c; if (c >= NCHUNK || !__any(act0 || act1)) break;
        LOADC(B4, c + 7); STEPC(B5, c); ++c; if (c >= NCHUNK || !__any(act0 || act1)) break;
        LOADC(B5, c + 7); STEPC(B6, c); ++c; if (c >= NCHUNK || !__any(act0 || act1)) break;
        LOADC(B6, c + 7); STEPC(B7, c); ++c; if (c >= NCHUNK || !__any(act0 || act1)) break;
    }

    // epilogue: same pinned op sequence as the reference for rt/choice
    v2f rt, choice;
    rt.x     = act0 ? __fadd_rn(MAXT_F, ndt)
                    : __fadd_rn(__fmul_rn((float)t_hit0, DT_F), ndt);
    rt.y     = act1 ? __fadd_rn(MAXT_F, ndt)
                    : __fadd_rn(__fmul_rn((float)t_hit1, DT_F), ndt);
    choice.x = act0 ? 0.5f : ((dv_hit0 > 0.0f) ? 1.0f : 0.0f);
    choice.y = act1 ? 0.5f : ((dv_hit1 > 0.0f) ? 1.0f : 0.0f);

    __builtin_nontemporal_store(rt,     (v2f*)(out + i0));
    __builtin_nontemporal_store(choice, (v2f*)(out + n + i0));
}

extern "C" void kernel_launch(void* const* d_in, const int* in_sizes, int n_in,
                              void* d_out, int out_size, void* d_ws, size_t ws_size,
                              hipStream_t stream) {
    const float* x     = (const float*)d_in[0];
    const float* noise = (const float*)d_in[1];
    const float* a     = (const float*)d_in[2];
    const float* z     = (const float*)d_in[3];
    const float* ndt   = (const float*)d_in[4];
    const float* dg    = (const float*)d_in[5];
    float* out = (float*)d_out;

    const int n = in_sizes[0];              // 65536 trials (even)
    const int pairs = n >> 1;               // 32768 threads
    const int block = 128;                  // -> 256 blocks = 1 per CU
    const int grid  = (pairs + block - 1) / block;
    ddm_sim_kernel<<<grid, block, 0, stream>>>(x, noise, a, z, ndt, dg, out, n);
}

// Round 8
// 82.126 us; speedup vs baseline: 1.9047x; 1.5054x over previous
//
#include <hip/hip_runtime.h>

#define STEPS   2000
#define DT_F    0.001f
#define EPS_F   1e-6f
#define MAXT_F  2.0f
#define CHUNK   10
#define NCHUNK  (STEPS / CHUNK)   // 200
// R8 = R5 structure (1024 waves = 4/CU, per-lane dword nt streams -- proven
// best in the R5/R6/R7 A/B) with pipeline depth pushed toward the vmcnt cap:
// CHUNK=10, 7 rotating buffers, prefetch distance 6 -> 60 outstanding loads
// per wave (<= 63 encodable), 61 KB/CU in flight (vs R5's 56/57 KB).

#define LOADC(BUF, c_) do {                                                   \
    const int cc = ((c_) < NCHUNK) ? (c_) : (NCHUNK - 1);                     \
    const float* bp = p + (size_t)(cc * CHUNK) * stride;                      \
    _Pragma("unroll")                                                         \
    for (int k = 0; k < CHUNK; ++k)                                           \
        BUF[k] = __builtin_nontemporal_load(bp + (size_t)k * stride);         \
} while (0)

// Exact reference rounding: dv = ((dv + drift*DT) + nscale*nz), separate
// mul/add, no FMA. Branchless hit latch: single abs-compare (fl(EPS-a) ==
// -fl(a-EPS) under RN symmetry -> identical to the two-sided test) + latches.
#define STEPC(BUF, cbase) do {                                                \
    _Pragma("unroll")                                                         \
    for (int k = 0; k < CHUNK; ++k) {                                         \
        dv = __fadd_rn(__fadd_rn(dv, drift_dt), __fmul_rn(nscale, BUF[k]));   \
        const bool hit = act && (__builtin_fabsf(dv) >= a_hi);                \
        t_hit  = hit ? ((cbase) * CHUNK + k) : t_hit;                         \
        dv_hit = hit ? dv : dv_hit;                                           \
        act    = act && !hit;                                                 \
    }                                                                         \
} while (0)

__global__ __launch_bounds__(256, 1) void ddm_sim_kernel(
    const float* __restrict__ x,
    const float* __restrict__ noise,
    const float* __restrict__ p_a,
    const float* __restrict__ p_z,
    const float* __restrict__ p_ndt,
    const float* __restrict__ p_dg,
    float* __restrict__ out,   // [0,n) = pred_rt, [n,2n) = pred_choice
    int n)
{
    const int i = blockIdx.x * blockDim.x + threadIdx.x;
    if (i >= n) return;

    const float a   = *p_a;
    const float z   = *p_z;
    const float ndt = *p_ndt;
    const float dg  = *p_dg;

    const float drift_dt = __fmul_rn(__fmul_rn(dg, x[i]), DT_F);
    const float nscale   = __fsqrt_rn(DT_F);     // SIGMA(=1) * sqrt(DT)
    const float a_hi     = __fsub_rn(a, EPS_F);  // a - EPS

    float dv     = __fmul_rn(z, a);
    float dv_hit = 0.0f;
    int   t_hit  = 0;
    bool  act    = true;

    const float* p      = noise + i;
    const size_t stride = (size_t)n;

    float B0[CHUNK], B1[CHUNK], B2[CHUNK], B3[CHUNK],
          B4[CHUNK], B5[CHUNK], B6[CHUNK];

    // prologue: fill pipeline 6 deep (60 loads in flight, 15 KB/wave)
    LOADC(B0, 0);
    LOADC(B1, 1);
    LOADC(B2, 2);
    LOADC(B3, 3);
    LOADC(B4, 4);
    LOADC(B5, 5);

    int c = 0;
    while (true) {
        LOADC(B6, c + 6); STEPC(B0, c); ++c; if (c >= NCHUNK || !__any(act)) break;
        LOADC(B0, c + 6); STEPC(B1, c); ++c; if (c >= NCHUNK || !__any(act)) break;
        LOADC(B1, c + 6); STEPC(B2, c); ++c; if (c >= NCHUNK || !__any(act)) break;
        LOADC(B2, c + 6); STEPC(B3, c); ++c; if (c >= NCHUNK || !__any(act)) break;
        LOADC(B3, c + 6); STEPC(B4, c); ++c; if (c >= NCHUNK || !__any(act)) break;
        LOADC(B4, c + 6); STEPC(B5, c); ++c; if (c >= NCHUNK || !__any(act)) break;
        LOADC(B5, c + 6); STEPC(B6, c); ++c; if (c >= NCHUNK || !__any(act)) break;
    }

    // epilogue: same pinned op sequence as the reference for rt/choice
    float rt, choice;
    if (act) {
        rt     = __fadd_rn(MAXT_F, ndt);
        choice = 0.5f;
    } else {
        rt     = __fadd_rn(__fmul_rn((float)t_hit, DT_F), ndt);
        choice = (dv_hit > 0.0f) ? 1.0f : 0.0f;   // hit_up <=> dv_hit >= a-eps > 0
    }
    __builtin_nontemporal_store(rt,     out + i);
    __builtin_nontemporal_store(choice, out + n + i);
}

extern "C" void kernel_launch(void* const* d_in, const int* in_sizes, int n_in,
                              void* d_out, int out_size, void* d_ws, size_t ws_size,
                              hipStream_t stream) {
    const float* x     = (const float*)d_in[0];
    const float* noise = (const float*)d_in[1];
    const float* a     = (const float*)d_in[2];
    const float* z     = (const float*)d_in[3];
    const float* ndt   = (const float*)d_in[4];
    const float* dg    = (const float*)d_in[5];
    float* out = (float*)d_out;

    const int n = in_sizes[0];              // 65536 trials
    const int block = 256;                  // 256 blocks -> 1 block/CU, 4 waves/CU
    const int grid  = (n + block - 1) / block;
    ddm_sim_kernel<<<grid, block, 0, stream>>>(x, noise, a, z, ndt, dg, out, n);
}